// Round 6
// baseline (572.084 us; speedup 1.0000x reference)
//
#include <hip/hip_runtime.h>
#include <hip/hip_bf16.h>
#include <math.h>

#define B_ 8
#define N_ 1024
#define H_ 14
#define DH_ 64
#define D_ 896
#define M_ (B_*N_)        // 8192 rows
#define DQKV_ 2688        // 3*D_

typedef __attribute__((ext_vector_type(8))) short bf16x8;
typedef __attribute__((ext_vector_type(4))) short bf16x4;
typedef __attribute__((ext_vector_type(4))) float f32x4;
typedef __attribute__((ext_vector_type(4))) unsigned u32x4;

__device__ __forceinline__ float bf2f(short s){
  unsigned u = ((unsigned)(unsigned short)s) << 16;
  union { unsigned u; float f; } c; c.u = u; return c.f;
}
__device__ __forceinline__ short f2bf(float f){
  union { float f; unsigned u; } c; c.f = f;
  unsigned u = c.u;
  unsigned r = (u + 0x7FFFu + ((u >> 16) & 1u)) >> 16;
  return (short)(unsigned short)r;
}
__device__ __forceinline__ float asf(unsigned u){
  union { unsigned u; float f; } c; c.u = u; return c.f;
}

// ---------------- LayerNorm: one block per row, f32 in -> bf16 out ----------------
__global__ __launch_bounds__(256) void ln_kernel(const float* __restrict__ x,
                                                 const float* __restrict__ g,
                                                 const float* __restrict__ bb,
                                                 short* __restrict__ y)
{
  int row = blockIdx.x;
  const float* xr = x + (size_t)row * D_;
  float s = 0.f, s2 = 0.f;
  for (int i = threadIdx.x; i < D_; i += 256){
    float v = xr[i]; s += v; s2 = fmaf(v, v, s2);
  }
  #pragma unroll
  for (int off = 32; off > 0; off >>= 1){
    s  += __shfl_down(s,  off, 64);
    s2 += __shfl_down(s2, off, 64);
  }
  __shared__ float rs_[4], rs2_[4];
  int wv = threadIdx.x >> 6;
  if ((threadIdx.x & 63) == 0){ rs_[wv] = s; rs2_[wv] = s2; }
  __syncthreads();
  float ts  = rs_[0] + rs_[1] + rs_[2] + rs_[3];
  float ts2 = rs2_[0] + rs2_[1] + rs2_[2] + rs2_[3];
  float mu  = ts * (1.f / D_);
  float var = ts2 * (1.f / D_) - mu * mu;
  float rstd = rsqrtf(var + 1e-5f);
  short* yr = y + (size_t)row * D_;
  for (int i = threadIdx.x; i < D_; i += 256){
    yr[i] = f2bf((xr[i] - mu) * rstd * g[i] + bb[i]);
  }
}

// ---------------- Transpose weights: f32 W[k][n] -> bf16 Wt[n][k] ----------------
__global__ __launch_bounds__(256) void transpose_kernel(
    const float* __restrict__ Wq, const float* __restrict__ Wk,
    const float* __restrict__ Wv, const float* __restrict__ Wo,
    short* __restrict__ WqkvT, short* __restrict__ WoT)
{
  __shared__ short t[64][72];
  int z = blockIdx.z;
  const float* W = (z == 0) ? Wq : (z == 1) ? Wk : (z == 2) ? Wv : Wo;
  int kb = blockIdx.x * 64, nb = blockIdx.y * 64;
  int c0 = (threadIdx.x & 7) * 8;
  int r0 = threadIdx.x >> 3;            // 0..31
  #pragma unroll
  for (int rr = 0; rr < 64; rr += 32){
    const float* src = &W[(size_t)(kb + r0 + rr) * D_ + nb + c0];
    float4 a = *(const float4*)src;
    float4 b = *(const float4*)(src + 4);
    short* dstl = &t[r0 + rr][c0];
    dstl[0] = f2bf(a.x); dstl[1] = f2bf(a.y); dstl[2] = f2bf(a.z); dstl[3] = f2bf(a.w);
    dstl[4] = f2bf(b.x); dstl[5] = f2bf(b.y); dstl[6] = f2bf(b.z); dstl[7] = f2bf(b.w);
  }
  __syncthreads();
  short* dst = (z < 3) ? (WqkvT + (size_t)(z * D_) * D_) : WoT;
  #pragma unroll
  for (int rr = 0; rr < 64; rr += 32){
    int n = nb + r0 + rr;
    bf16x8 v;
    #pragma unroll
    for (int j = 0; j < 8; j++) v[j] = t[c0 + j][r0 + rr];
    *(bf16x8*)&dst[(size_t)n * D_ + kb + c0] = v;
  }
}

// ---------------- Prep: csb[k][q] = packed bf16(cosB, sinB); adjT[k][q] = bf16 adj^T ----
__global__ __launch_bounds__(256) void prep_kernel(
    const float* __restrict__ adj, const float* __restrict__ brg,
    unsigned* __restrict__ csb, short* __restrict__ adjT)
{
  int kt = blockIdx.x, qt = blockIdx.y;
  int r  = threadIdx.x >> 2;          // 0..63
  int c0 = (threadIdx.x & 3) * 16;    // 0..48
  // csb from brg (both [k][q], coalesced)
  {
    int k = kt * 64 + r;
    const float* bp = brg + (size_t)k * N_ + qt * 64 + c0;
    unsigned* cp = csb + (size_t)k * N_ + qt * 64 + c0;
    #pragma unroll
    for (int i = 0; i < 16; i += 4){
      float4 bv = *(const float4*)(bp + i);
      float b4[4] = { bv.x, bv.y, bv.z, bv.w };
      unsigned o[4];
      #pragma unroll
      for (int j = 0; j < 4; j++){
        float Br = (b4[j] + 180.f) * 0.017453292519943295f;
        float sB, cB;
        __sincosf(Br, &sB, &cB);
        o[j] = ((unsigned)(unsigned short)f2bf(cB)) |
               (((unsigned)(unsigned short)f2bf(sB)) << 16);
      }
      *(uint4*)(cp + i) = make_uint4(o[0], o[1], o[2], o[3]);
    }
  }
  // adjT via LDS transpose
  __shared__ short tt[64][72];
  {
    int q = qt * 64 + r;
    const float* ap = adj + (size_t)q * N_ + kt * 64 + c0;
    #pragma unroll
    for (int i = 0; i < 16; i += 4){
      float4 av = *(const float4*)(ap + i);
      tt[r][c0 + i]     = f2bf(av.x);
      tt[r][c0 + i + 1] = f2bf(av.y);
      tt[r][c0 + i + 2] = f2bf(av.z);
      tt[r][c0 + i + 3] = f2bf(av.w);
    }
  }
  __syncthreads();
  {
    int k = kt * 64 + r;
    short* op = adjT + (size_t)k * N_ + qt * 64 + c0;
    bf16x8 v0, v1;
    #pragma unroll
    for (int j = 0; j < 8; j++){ v0[j] = tt[c0 + j][r]; v1[j] = tt[c0 + 8 + j][r]; }
    *(bf16x8*)op = v0;
    *(bf16x8*)(op + 8) = v1;
  }
}

// ---------------- MFMA GEMM: C[M x N] = A[M x K] * Bt[N x K]^T ----------------
__global__ __launch_bounds__(256) void gemm_bt(const short* __restrict__ A,
                                               const short* __restrict__ Bt,
                                               short* __restrict__ C,
                                               float* __restrict__ Cf,
                                               const float* __restrict__ residf,
                                               int N)
{
  const int K = D_;
  __shared__ short As[128 * 32];
  __shared__ short Bs[128 * 32];
  int tid  = threadIdx.x;
  int wave = tid >> 6;
  int lane = tid & 63;
  int quad = lane >> 4;
  int l16  = lane & 15;
  int wr = wave >> 1, wc = wave & 1;
  int m0 = blockIdx.x * 128;
  int n0 = blockIdx.y * 128;

  f32x4 acc[4][4];
  #pragma unroll
  for (int i = 0; i < 4; i++)
    #pragma unroll
    for (int j = 0; j < 4; j++)
      acc[i][j] = (f32x4){0.f, 0.f, 0.f, 0.f};

  for (int k0 = 0; k0 < K; k0 += 32){
    __syncthreads();
    #pragma unroll
    for (int it = 0; it < 2; ++it){
      int c   = tid + it * 256;
      int row = c >> 2;
      int cc  = c & 3;
      const short* ga = A  + (size_t)(m0 + row) * K + k0 + cc * 8;
      const short* gb = Bt + (size_t)(n0 + row) * K + k0 + cc * 8;
      short* la = As + (size_t)(wave * 64 + it * 256) * 8;
      short* lb = Bs + (size_t)(wave * 64 + it * 256) * 8;
      __builtin_amdgcn_global_load_lds((const __attribute__((address_space(1))) void*)ga,
                                       (__attribute__((address_space(3))) void*)la, 16, 0, 0);
      __builtin_amdgcn_global_load_lds((const __attribute__((address_space(1))) void*)gb,
                                       (__attribute__((address_space(3))) void*)lb, 16, 0, 0);
    }
    __syncthreads();

    bf16x8 af[4], bfr[4];
    #pragma unroll
    for (int i = 0; i < 4; i++)
      af[i] = *(const bf16x8*)(As + (size_t)(wr * 64 + i * 16 + l16) * 32 + quad * 8);
    #pragma unroll
    for (int j = 0; j < 4; j++)
      bfr[j] = *(const bf16x8*)(Bs + (size_t)(wc * 64 + j * 16 + l16) * 32 + quad * 8);
    #pragma unroll
    for (int i = 0; i < 4; i++)
      #pragma unroll
      for (int j = 0; j < 4; j++)
        acc[i][j] = __builtin_amdgcn_mfma_f32_16x16x32_bf16(af[i], bfr[j], acc[i][j], 0, 0, 0);
  }

  #pragma unroll
  for (int i = 0; i < 4; i++){
    #pragma unroll
    for (int rr = 0; rr < 4; rr++){
      int r = m0 + wr * 64 + i * 16 + quad * 4 + rr;
      size_t rowoff = (size_t)r * N;
      #pragma unroll
      for (int j = 0; j < 4; j++){
        int cidx = n0 + wc * 64 + j * 16 + l16;
        float v = acc[i][j][rr];
        if (Cf){
          Cf[rowoff + cidx] = v + residf[rowoff + cidx];
        } else {
          C[rowoff + cidx] = f2bf(v);
        }
      }
    }
  }
}

// ---------------- RoPE in place on Q,K halves; Q also scaled by 1/8 ----------------
__global__ __launch_bounds__(256) void rope_kernel(short* __restrict__ QKV)
{
  int idx  = blockIdx.x * 256 + threadIdx.x;
  int mrow = idx / D_;
  int r    = idx - mrow * D_;
  int mat  = r / 448;        // 0 = Q, 1 = K
  int hi   = r - mat * 448;
  int h    = hi >> 5;
  int i    = hi & 31;
  int n    = mrow & (N_ - 1);
  float invf = exp2f(-(float)i * 0.4152410118609203f);  // 10000^(-i/32)
  float ang  = (float)n * invf;
  float sv, cv;
  __sincosf(ang, &sv, &cv);
  size_t base = (size_t)mrow * DQKV_ + (size_t)mat * D_ + h * DH_ + i;
  float x1 = bf2f(QKV[base]);
  float x2 = bf2f(QKV[base + 32]);
  float o1 = x1 * cv - x2 * sv;
  float o2 = x2 * cv + x1 * sv;
  if (mat == 0){ o1 *= 0.125f; o2 *= 0.125f; }   // fold 1/sqrt(Dh) into Q
  QKV[base]      = f2bf(o1);
  QKV[base + 32] = f2bf(o2);
}

// ---------------- MFMA flash attention, fixed-max softmax ----------------
// block = (b, h, 128-q tile); 8 waves x 16 q-rows; 64-key tiles; K/V/P in LDS,
// csb/adjT read directly from global (no intra-block reuse -> no staging).
#define M0_ 12.0f
__global__ __launch_bounds__(512, 6) void attn_kernel(
    const short* __restrict__ QKV,
    const unsigned* __restrict__ csb,   // [k][q] packed (cosB lo16, sinB hi16)
    const short* __restrict__ adjT,     // [k][q] bf16
    const float* __restrict__ wind_dirs,
    const float* __restrict__ wind_w,
    const float* __restrict__ wind_b,
    short* __restrict__ outb)
{
  __shared__ short K_s[64 * 72];       // K[k][d]
  __shared__ short V_t[64 * 76];       // V^T[d][k]
  __shared__ short P_s[128 * 76];      // P[q][k]

  int bid = blockIdx.x;
  int qt  = bid & 7;
  int hh  = (bid >> 3) % H_;
  int b   = bid / (8 * H_);
  int q0  = qt * 128;

  int t    = threadIdx.x;
  int w    = t >> 6;          // 0..7
  int lane = t & 63;
  int quad = lane >> 4;
  int l16  = lane & 15;

  // Q fragments (A-operand): m = l16 (q row in wave), k = kc*32 + quad*8 + j
  const short* qp = QKV + ((size_t)(b * N_) + q0 + w * 16 + l16) * DQKV_ + hh * DH_;
  bf16x8 qf0 = *(const bf16x8*)(qp + quad * 8);
  bf16x8 qf1 = *(const bf16x8*)(qp + 32 + quad * 8);

  // wind dir trig per q-row (q = q0 + w*16 + quad*4 + rr)
  float cA[4], sA[4];
  #pragma unroll
  for (int rr = 0; rr < 4; rr++){
    float wd = wind_dirs[(size_t)b * N_ + q0 + w * 16 + quad * 4 + rr];
    float A  = wd * 0.017453292519943295f;
    sA[rr] = __sinf(A);
    cA[rr] = __cosf(A);
  }
  float w0 = wind_w[hh];
  float w1 = wind_w[H_ + hh];
  float wb = wind_b[hh];

  float l[4] = {0.f, 0.f, 0.f, 0.f};
  f32x4 O[4];
  #pragma unroll
  for (int dc = 0; dc < 4; dc++) O[dc] = (f32x4){0.f, 0.f, 0.f, 0.f};

  // staging indices
  int kr  = t >> 3, kc8 = (t & 7) * 8;          // K rows (1 bf16x8 per thread)
  int vk2 = (t >> 4) * 2, vd4 = (t & 15) * 4;   // V: 2 k-rows x 4 d per thread

  for (int kt = 0; kt < 16; ++kt){
    int k0 = kt * 64;
    __syncthreads();
    {
      // K tile: K_s[k][d]
      const short* kg = QKV + ((size_t)(b * N_) + k0 + kr) * DQKV_ + D_ + hh * DH_ + kc8;
      *(bf16x8*)(K_s + kr * 72 + kc8) = *(const bf16x8*)kg;
      // V tile transposed: V_t[d][k], write k-pairs as u32
      const short* vg = QKV + ((size_t)(b * N_) + k0 + vk2) * DQKV_ + 2 * D_ + hh * DH_ + vd4;
      bf16x4 v0 = *(const bf16x4*)vg;
      bf16x4 v1 = *(const bf16x4*)(vg + DQKV_);
      #pragma unroll
      for (int j = 0; j < 4; j++){
        unsigned pv = ((unsigned)(unsigned short)v0[j]) |
                      (((unsigned)(unsigned short)v1[j]) << 16);
        *(unsigned*)(V_t + (vd4 + j) * 76 + vk2) = pv;
      }
    }
    __syncthreads();

    // issue bias-input global loads early (hide under MFMA)
    u32x4 cs4a[4]; bf16x4 av4a[4];
    #pragma unroll
    for (int jc = 0; jc < 4; jc++){
      size_t off = (size_t)(k0 + jc * 16 + l16) * N_ + q0 + w * 16 + quad * 4;
      cs4a[jc] = *(const u32x4*)(csb + off);
      av4a[jc] = *(const bf16x4*)(adjT + off);
    }

    // S = Q K^T  (rows q, cols k)
    f32x4 S[4];
    #pragma unroll
    for (int jc = 0; jc < 4; jc++){
      S[jc] = (f32x4){0.f, 0.f, 0.f, 0.f};
      bf16x8 kf0 = *(const bf16x8*)(K_s + (jc * 16 + l16) * 72 + quad * 8);
      bf16x8 kf1 = *(const bf16x8*)(K_s + (jc * 16 + l16) * 72 + 32 + quad * 8);
      S[jc] = __builtin_amdgcn_mfma_f32_16x16x32_bf16(qf0, kf0, S[jc], 0, 0, 0);
      S[jc] = __builtin_amdgcn_mfma_f32_16x16x32_bf16(qf1, kf1, S[jc], 0, 0, 0);
    }

    // bias + mask + exp(S + bias - M0), accumulate l, write P
    #pragma unroll
    for (int jc = 0; jc < 4; jc++){
      #pragma unroll
      for (int rr = 0; rr < 4; rr++){
        unsigned u = cs4a[jc][rr];
        float cB = asf(u << 16);
        float sB = asf(u & 0xffff0000u);
        float av = bf2f(av4a[jc][rr]);
        float align = cA[rr] * cB + sA[rr] * sB;
        float z  = fmaf(align, w0, fmaf(av, w1, wb));
        float e2 = __expf(2.f * z);
        float bias = 1.f - 2.f * __builtin_amdgcn_rcpf(e2 + 1.f);
        float sv = (av > 0.f ? S[jc][rr] : -1e30f) + (bias - M0_);
        float e = __expf(sv);
        S[jc][rr] = e;
        l[rr] += e;
        P_s[(w * 16 + quad * 4 + rr) * 76 + jc * 16 + l16] = f2bf(e);
      }
    }

    // PV (A-layout read of own P rows; V_t from barrier-protected stage)
    #pragma unroll
    for (int kc = 0; kc < 2; kc++){
      const short* pp = P_s + (w * 16 + l16) * 76 + kc * 32 + quad * 8;
      bf16x4 p0 = *(const bf16x4*)pp;
      bf16x4 p1 = *(const bf16x4*)(pp + 4);
      bf16x8 pf = { p0[0], p0[1], p0[2], p0[3], p1[0], p1[1], p1[2], p1[3] };
      #pragma unroll
      for (int dc = 0; dc < 4; dc++){
        const short* vp = V_t + (dc * 16 + l16) * 76 + kc * 32 + quad * 8;
        bf16x4 u0 = *(const bf16x4*)vp;
        bf16x4 u1 = *(const bf16x4*)(vp + 4);
        bf16x8 vf = { u0[0], u0[1], u0[2], u0[3], u1[0], u1[1], u1[2], u1[3] };
        O[dc] = __builtin_amdgcn_mfma_f32_16x16x32_bf16(pf, vf, O[dc], 0, 0, 0);
      }
    }
  }

  // epilogue: reduce l across the 16 lanes of the row group, O / l, write bf16
  float rl[4];
  #pragma unroll
  for (int rr = 0; rr < 4; rr++){
    float rs = l[rr];
    rs += __shfl_xor(rs, 1);
    rs += __shfl_xor(rs, 2);
    rs += __shfl_xor(rs, 4);
    rs += __shfl_xor(rs, 8);
    rl[rr] = 1.f / rs;
  }
  short* op = outb + ((size_t)(b * N_) + q0 + w * 16) * D_ + hh * DH_;
  #pragma unroll
  for (int rr = 0; rr < 4; rr++)
    #pragma unroll
    for (int dc = 0; dc < 4; dc++)
      op[(size_t)(quad * 4 + rr) * D_ + dc * 16 + l16] = f2bf(O[dc][rr] * rl[rr]);
}

extern "C" void kernel_launch(void* const* d_in, const int* in_sizes, int n_in,
                              void* d_out, int out_size, void* d_ws, size_t ws_size,
                              hipStream_t stream)
{
  const float* nf   = (const float*)d_in[0];
  const float* adj  = (const float*)d_in[1];
  const float* wdir = (const float*)d_in[2];
  const float* brg  = (const float*)d_in[3];
  const float* Wq   = (const float*)d_in[4];
  const float* Wk   = (const float*)d_in[5];
  const float* Wv   = (const float*)d_in[6];
  const float* Wo   = (const float*)d_in[7];
  const float* lng  = (const float*)d_in[8];
  const float* lnb  = (const float*)d_in[9];
  const float* ww   = (const float*)d_in[10];
  const float* wbb  = (const float*)d_in[11];
  float* out = (float*)d_out;

  short* xln   = (short*)d_ws;                        // M_*D_ (reused as attn out)
  short* WqkvT = xln   + (size_t)M_ * D_;             // 2688*896
  short* WoT   = WqkvT + (size_t)DQKV_ * D_;          // 896*896
  short* QKV   = WoT   + (size_t)D_ * D_;             // M_*2688
  unsigned* csb = (unsigned*)(QKV + (size_t)M_ * DQKV_); // 1024*1024 u32
  short* adjT  = (short*)(csb + (size_t)N_ * N_);     // 1024*1024 bf16

  ln_kernel<<<M_, 256, 0, stream>>>(nf, lng, lnb, xln);
  transpose_kernel<<<dim3(14, 14, 4), 256, 0, stream>>>(Wq, Wk, Wv, Wo, WqkvT, WoT);
  prep_kernel<<<dim3(16, 16), 256, 0, stream>>>(adj, brg, csb, adjT);
  gemm_bt<<<dim3(M_ / 128, DQKV_ / 128), 256, 0, stream>>>(xln, WqkvT, QKV, nullptr, nullptr, DQKV_);
  rope_kernel<<<(M_ * D_) / 256, 256, 0, stream>>>(QKV);
  attn_kernel<<<B_ * H_ * 8, 512, 0, stream>>>(QKV, csb, adjT, wdir, ww, wbb, xln);
  gemm_bt<<<dim3(M_ / 128, D_ / 128), 256, 0, stream>>>(xln, WoT, nullptr, out, nf, D_);
}

// Round 7
// 378.713 us; speedup vs baseline: 1.5106x; 1.5106x over previous
//
#include <hip/hip_runtime.h>
#include <hip/hip_bf16.h>
#include <math.h>

#define B_ 8
#define N_ 1024
#define H_ 14
#define DH_ 64
#define D_ 896
#define M_ (B_*N_)        // 8192 rows
#define DQKV_ 2688        // 3*D_

typedef __attribute__((ext_vector_type(8))) short bf16x8;
typedef __attribute__((ext_vector_type(4))) short bf16x4;
typedef __attribute__((ext_vector_type(4))) float f32x4;
typedef __attribute__((ext_vector_type(4))) unsigned u32x4;

__device__ __forceinline__ float bf2f(short s){
  unsigned u = ((unsigned)(unsigned short)s) << 16;
  union { unsigned u; float f; } c; c.u = u; return c.f;
}
__device__ __forceinline__ short f2bf(float f){
  union { float f; unsigned u; } c; c.f = f;
  unsigned u = c.u;
  unsigned r = (u + 0x7FFFu + ((u >> 16) & 1u)) >> 16;
  return (short)(unsigned short)r;
}
__device__ __forceinline__ float asf(unsigned u){
  union { unsigned u; float f; } c; c.u = u; return c.f;
}

// ---------------- LayerNorm: one block per row, f32 in -> bf16 out ----------------
__global__ __launch_bounds__(256) void ln_kernel(const float* __restrict__ x,
                                                 const float* __restrict__ g,
                                                 const float* __restrict__ bb,
                                                 short* __restrict__ y)
{
  int row = blockIdx.x;
  const float* xr = x + (size_t)row * D_;
  float s = 0.f, s2 = 0.f;
  for (int i = threadIdx.x; i < D_; i += 256){
    float v = xr[i]; s += v; s2 = fmaf(v, v, s2);
  }
  #pragma unroll
  for (int off = 32; off > 0; off >>= 1){
    s  += __shfl_down(s,  off, 64);
    s2 += __shfl_down(s2, off, 64);
  }
  __shared__ float rs_[4], rs2_[4];
  int wv = threadIdx.x >> 6;
  if ((threadIdx.x & 63) == 0){ rs_[wv] = s; rs2_[wv] = s2; }
  __syncthreads();
  float ts  = rs_[0] + rs_[1] + rs_[2] + rs_[3];
  float ts2 = rs2_[0] + rs2_[1] + rs2_[2] + rs2_[3];
  float mu  = ts * (1.f / D_);
  float var = ts2 * (1.f / D_) - mu * mu;
  float rstd = rsqrtf(var + 1e-5f);
  short* yr = y + (size_t)row * D_;
  for (int i = threadIdx.x; i < D_; i += 256){
    yr[i] = f2bf((xr[i] - mu) * rstd * g[i] + bb[i]);
  }
}

// ---------------- Transpose weights: f32 W[k][n] -> bf16 Wt[n][k] ----------------
__global__ __launch_bounds__(256) void transpose_kernel(
    const float* __restrict__ Wq, const float* __restrict__ Wk,
    const float* __restrict__ Wv, const float* __restrict__ Wo,
    short* __restrict__ WqkvT, short* __restrict__ WoT)
{
  __shared__ short t[64][72];
  int z = blockIdx.z;
  const float* W = (z == 0) ? Wq : (z == 1) ? Wk : (z == 2) ? Wv : Wo;
  int kb = blockIdx.x * 64, nb = blockIdx.y * 64;
  int c0 = (threadIdx.x & 7) * 8;
  int r0 = threadIdx.x >> 3;            // 0..31
  #pragma unroll
  for (int rr = 0; rr < 64; rr += 32){
    const float* src = &W[(size_t)(kb + r0 + rr) * D_ + nb + c0];
    float4 a = *(const float4*)src;
    float4 b = *(const float4*)(src + 4);
    short* dstl = &t[r0 + rr][c0];
    dstl[0] = f2bf(a.x); dstl[1] = f2bf(a.y); dstl[2] = f2bf(a.z); dstl[3] = f2bf(a.w);
    dstl[4] = f2bf(b.x); dstl[5] = f2bf(b.y); dstl[6] = f2bf(b.z); dstl[7] = f2bf(b.w);
  }
  __syncthreads();
  short* dst = (z < 3) ? (WqkvT + (size_t)(z * D_) * D_) : WoT;
  #pragma unroll
  for (int rr = 0; rr < 64; rr += 32){
    int n = nb + r0 + rr;
    bf16x8 v;
    #pragma unroll
    for (int j = 0; j < 8; j++) v[j] = t[c0 + j][r0 + rr];
    *(bf16x8*)&dst[(size_t)n * D_ + kb + c0] = v;
  }
}

// ---------------- Prep: csb[k][q] = packed bf16(cosB, sinB); adjT[k][q] = bf16 adj^T ----
__global__ __launch_bounds__(256) void prep_kernel(
    const float* __restrict__ adj, const float* __restrict__ brg,
    unsigned* __restrict__ csb, short* __restrict__ adjT)
{
  int kt = blockIdx.x, qt = blockIdx.y;
  int r  = threadIdx.x >> 2;          // 0..63
  int c0 = (threadIdx.x & 3) * 16;    // 0..48
  // csb from brg (both [k][q], coalesced)
  {
    int k = kt * 64 + r;
    const float* bp = brg + (size_t)k * N_ + qt * 64 + c0;
    unsigned* cp = csb + (size_t)k * N_ + qt * 64 + c0;
    #pragma unroll
    for (int i = 0; i < 16; i += 4){
      float4 bv = *(const float4*)(bp + i);
      float b4[4] = { bv.x, bv.y, bv.z, bv.w };
      unsigned o[4];
      #pragma unroll
      for (int j = 0; j < 4; j++){
        float Br = (b4[j] + 180.f) * 0.017453292519943295f;
        float sB, cB;
        __sincosf(Br, &sB, &cB);
        o[j] = ((unsigned)(unsigned short)f2bf(cB)) |
               (((unsigned)(unsigned short)f2bf(sB)) << 16);
      }
      *(uint4*)(cp + i) = make_uint4(o[0], o[1], o[2], o[3]);
    }
  }
  // adjT via LDS transpose
  __shared__ short tt[64][72];
  {
    int q = qt * 64 + r;
    const float* ap = adj + (size_t)q * N_ + kt * 64 + c0;
    #pragma unroll
    for (int i = 0; i < 16; i += 4){
      float4 av = *(const float4*)(ap + i);
      tt[r][c0 + i]     = f2bf(av.x);
      tt[r][c0 + i + 1] = f2bf(av.y);
      tt[r][c0 + i + 2] = f2bf(av.z);
      tt[r][c0 + i + 3] = f2bf(av.w);
    }
  }
  __syncthreads();
  {
    int k = kt * 64 + r;
    short* op = adjT + (size_t)k * N_ + qt * 64 + c0;
    bf16x8 v0, v1;
    #pragma unroll
    for (int j = 0; j < 8; j++){ v0[j] = tt[c0 + j][r]; v1[j] = tt[c0 + 8 + j][r]; }
    *(bf16x8*)op = v0;
    *(bf16x8*)(op + 8) = v1;
  }
}

// ---------------- MFMA GEMM: C[M x N] = A[M x K] * Bt[N x K]^T ----------------
__global__ __launch_bounds__(256) void gemm_bt(const short* __restrict__ A,
                                               const short* __restrict__ Bt,
                                               short* __restrict__ C,
                                               float* __restrict__ Cf,
                                               const float* __restrict__ residf,
                                               int N)
{
  const int K = D_;
  __shared__ short As[128 * 32];
  __shared__ short Bs[128 * 32];
  int tid  = threadIdx.x;
  int wave = tid >> 6;
  int lane = tid & 63;
  int quad = lane >> 4;
  int l16  = lane & 15;
  int wr = wave >> 1, wc = wave & 1;
  int m0 = blockIdx.x * 128;
  int n0 = blockIdx.y * 128;

  f32x4 acc[4][4];
  #pragma unroll
  for (int i = 0; i < 4; i++)
    #pragma unroll
    for (int j = 0; j < 4; j++)
      acc[i][j] = (f32x4){0.f, 0.f, 0.f, 0.f};

  for (int k0 = 0; k0 < K; k0 += 32){
    __syncthreads();
    #pragma unroll
    for (int it = 0; it < 2; ++it){
      int c   = tid + it * 256;
      int row = c >> 2;
      int cc  = c & 3;
      const short* ga = A  + (size_t)(m0 + row) * K + k0 + cc * 8;
      const short* gb = Bt + (size_t)(n0 + row) * K + k0 + cc * 8;
      short* la = As + (size_t)(wave * 64 + it * 256) * 8;
      short* lb = Bs + (size_t)(wave * 64 + it * 256) * 8;
      __builtin_amdgcn_global_load_lds((const __attribute__((address_space(1))) void*)ga,
                                       (__attribute__((address_space(3))) void*)la, 16, 0, 0);
      __builtin_amdgcn_global_load_lds((const __attribute__((address_space(1))) void*)gb,
                                       (__attribute__((address_space(3))) void*)lb, 16, 0, 0);
    }
    __syncthreads();

    bf16x8 af[4], bfr[4];
    #pragma unroll
    for (int i = 0; i < 4; i++)
      af[i] = *(const bf16x8*)(As + (size_t)(wr * 64 + i * 16 + l16) * 32 + quad * 8);
    #pragma unroll
    for (int j = 0; j < 4; j++)
      bfr[j] = *(const bf16x8*)(Bs + (size_t)(wc * 64 + j * 16 + l16) * 32 + quad * 8);
    #pragma unroll
    for (int i = 0; i < 4; i++)
      #pragma unroll
      for (int j = 0; j < 4; j++)
        acc[i][j] = __builtin_amdgcn_mfma_f32_16x16x32_bf16(af[i], bfr[j], acc[i][j], 0, 0, 0);
  }

  #pragma unroll
  for (int i = 0; i < 4; i++){
    #pragma unroll
    for (int rr = 0; rr < 4; rr++){
      int r = m0 + wr * 64 + i * 16 + quad * 4 + rr;
      size_t rowoff = (size_t)r * N;
      #pragma unroll
      for (int j = 0; j < 4; j++){
        int cidx = n0 + wc * 64 + j * 16 + l16;
        float v = acc[i][j][rr];
        if (Cf){
          Cf[rowoff + cidx] = v + residf[rowoff + cidx];
        } else {
          C[rowoff + cidx] = f2bf(v);
        }
      }
    }
  }
}

// ---------------- RoPE in place on Q,K halves; Q also scaled by 1/8 ----------------
__global__ __launch_bounds__(256) void rope_kernel(short* __restrict__ QKV)
{
  int idx  = blockIdx.x * 256 + threadIdx.x;
  int mrow = idx / D_;
  int r    = idx - mrow * D_;
  int mat  = r / 448;        // 0 = Q, 1 = K
  int hi   = r - mat * 448;
  int h    = hi >> 5;
  int i    = hi & 31;
  int n    = mrow & (N_ - 1);
  float invf = exp2f(-(float)i * 0.4152410118609203f);  // 10000^(-i/32)
  float ang  = (float)n * invf;
  float sv, cv;
  __sincosf(ang, &sv, &cv);
  size_t base = (size_t)mrow * DQKV_ + (size_t)mat * D_ + h * DH_ + i;
  float x1 = bf2f(QKV[base]);
  float x2 = bf2f(QKV[base + 32]);
  float o1 = x1 * cv - x2 * sv;
  float o2 = x2 * cv + x1 * sv;
  if (mat == 0){ o1 *= 0.125f; o2 *= 0.125f; }   // fold 1/sqrt(Dh) into Q
  QKV[base]      = f2bf(o1);
  QKV[base + 32] = f2bf(o2);
}

// ---------------- MFMA flash attention, fixed-max softmax ----------------
// block = (b, h, 128-q tile); 8 waves x 16 q-rows; 64-key tiles; K/V/P in LDS,
// csb/adjT read directly from global (no intra-block reuse -> no staging; L3-resident).
// __launch_bounds__(512,4): 128-VGPR budget. (512,6) forced 40 VGPRs -> loop spill,
// +700 MB HBM scratch traffic (round-6 counters). Do not tighten.
#define M0_ 12.0f
__global__ __launch_bounds__(512, 4) void attn_kernel(
    const short* __restrict__ QKV,
    const unsigned* __restrict__ csb,   // [k][q] packed (cosB lo16, sinB hi16)
    const short* __restrict__ adjT,     // [k][q] bf16
    const float* __restrict__ wind_dirs,
    const float* __restrict__ wind_w,
    const float* __restrict__ wind_b,
    short* __restrict__ outb)
{
  __shared__ short K_s[64 * 72];       // K[k][d]
  __shared__ short V_t[64 * 76];       // V^T[d][k]
  __shared__ short P_s[128 * 76];      // P[q][k]

  int bid = blockIdx.x;
  int qt  = bid & 7;
  int hh  = (bid >> 3) % H_;
  int b   = bid / (8 * H_);
  int q0  = qt * 128;

  int t    = threadIdx.x;
  int w    = t >> 6;          // 0..7
  int lane = t & 63;
  int quad = lane >> 4;
  int l16  = lane & 15;

  // Q fragments (A-operand): m = l16 (q row in wave), k = kc*32 + quad*8 + j
  const short* qp = QKV + ((size_t)(b * N_) + q0 + w * 16 + l16) * DQKV_ + hh * DH_;
  bf16x8 qf0 = *(const bf16x8*)(qp + quad * 8);
  bf16x8 qf1 = *(const bf16x8*)(qp + 32 + quad * 8);

  // wind dir trig per q-row (q = q0 + w*16 + quad*4 + rr)
  float cA[4], sA[4];
  #pragma unroll
  for (int rr = 0; rr < 4; rr++){
    float wd = wind_dirs[(size_t)b * N_ + q0 + w * 16 + quad * 4 + rr];
    float A  = wd * 0.017453292519943295f;
    sA[rr] = __sinf(A);
    cA[rr] = __cosf(A);
  }
  float w0 = wind_w[hh];
  float w1 = wind_w[H_ + hh];
  float wb = wind_b[hh];

  float l[4] = {0.f, 0.f, 0.f, 0.f};
  f32x4 O[4];
  #pragma unroll
  for (int dc = 0; dc < 4; dc++) O[dc] = (f32x4){0.f, 0.f, 0.f, 0.f};

  // staging indices
  int kr  = t >> 3, kc8 = (t & 7) * 8;          // K rows (1 bf16x8 per thread)
  int vk2 = (t >> 4) * 2, vd4 = (t & 15) * 4;   // V: 2 k-rows x 4 d per thread

  for (int kt = 0; kt < 16; ++kt){
    int k0 = kt * 64;
    __syncthreads();
    {
      // K tile: K_s[k][d]
      const short* kg = QKV + ((size_t)(b * N_) + k0 + kr) * DQKV_ + D_ + hh * DH_ + kc8;
      *(bf16x8*)(K_s + kr * 72 + kc8) = *(const bf16x8*)kg;
      // V tile transposed: V_t[d][k], write k-pairs as u32
      const short* vg = QKV + ((size_t)(b * N_) + k0 + vk2) * DQKV_ + 2 * D_ + hh * DH_ + vd4;
      bf16x4 v0 = *(const bf16x4*)vg;
      bf16x4 v1 = *(const bf16x4*)(vg + DQKV_);
      #pragma unroll
      for (int j = 0; j < 4; j++){
        unsigned pv = ((unsigned)(unsigned short)v0[j]) |
                      (((unsigned)(unsigned short)v1[j]) << 16);
        *(unsigned*)(V_t + (vd4 + j) * 76 + vk2) = pv;
      }
    }
    __syncthreads();

    // issue bias-input global loads early (hide under MFMA)
    u32x4 cs4a[4]; bf16x4 av4a[4];
    #pragma unroll
    for (int jc = 0; jc < 4; jc++){
      size_t off = (size_t)(k0 + jc * 16 + l16) * N_ + q0 + w * 16 + quad * 4;
      cs4a[jc] = *(const u32x4*)(csb + off);
      av4a[jc] = *(const bf16x4*)(adjT + off);
    }

    // S = Q K^T  (rows q, cols k)
    f32x4 S[4];
    #pragma unroll
    for (int jc = 0; jc < 4; jc++){
      S[jc] = (f32x4){0.f, 0.f, 0.f, 0.f};
      bf16x8 kf0 = *(const bf16x8*)(K_s + (jc * 16 + l16) * 72 + quad * 8);
      bf16x8 kf1 = *(const bf16x8*)(K_s + (jc * 16 + l16) * 72 + 32 + quad * 8);
      S[jc] = __builtin_amdgcn_mfma_f32_16x16x32_bf16(qf0, kf0, S[jc], 0, 0, 0);
      S[jc] = __builtin_amdgcn_mfma_f32_16x16x32_bf16(qf1, kf1, S[jc], 0, 0, 0);
    }

    // bias + mask + exp(S + bias - M0), accumulate l, write P
    #pragma unroll
    for (int jc = 0; jc < 4; jc++){
      #pragma unroll
      for (int rr = 0; rr < 4; rr++){
        unsigned u = cs4a[jc][rr];
        float cB = asf(u << 16);
        float sB = asf(u & 0xffff0000u);
        float av = bf2f(av4a[jc][rr]);
        float align = cA[rr] * cB + sA[rr] * sB;
        float z  = fmaf(align, w0, fmaf(av, w1, wb));
        float e2 = __expf(2.f * z);
        float bias = 1.f - 2.f * __builtin_amdgcn_rcpf(e2 + 1.f);
        float sv = (av > 0.f ? S[jc][rr] : -1e30f) + (bias - M0_);
        float e = __expf(sv);
        S[jc][rr] = e;
        l[rr] += e;
        P_s[(w * 16 + quad * 4 + rr) * 76 + jc * 16 + l16] = f2bf(e);
      }
    }

    // PV (A-layout read of own P rows; V_t from barrier-protected stage)
    #pragma unroll
    for (int kc = 0; kc < 2; kc++){
      const short* pp = P_s + (w * 16 + l16) * 76 + kc * 32 + quad * 8;
      bf16x4 p0 = *(const bf16x4*)pp;
      bf16x4 p1 = *(const bf16x4*)(pp + 4);
      bf16x8 pf = { p0[0], p0[1], p0[2], p0[3], p1[0], p1[1], p1[2], p1[3] };
      #pragma unroll
      for (int dc = 0; dc < 4; dc++){
        const short* vp = V_t + (dc * 16 + l16) * 76 + kc * 32 + quad * 8;
        bf16x4 u0 = *(const bf16x4*)vp;
        bf16x4 u1 = *(const bf16x4*)(vp + 4);
        bf16x8 vf = { u0[0], u0[1], u0[2], u0[3], u1[0], u1[1], u1[2], u1[3] };
        O[dc] = __builtin_amdgcn_mfma_f32_16x16x32_bf16(pf, vf, O[dc], 0, 0, 0);
      }
    }
  }

  // epilogue: reduce l across the 16 lanes of the row group, O / l, write bf16
  float rl[4];
  #pragma unroll
  for (int rr = 0; rr < 4; rr++){
    float rs = l[rr];
    rs += __shfl_xor(rs, 1);
    rs += __shfl_xor(rs, 2);
    rs += __shfl_xor(rs, 4);
    rs += __shfl_xor(rs, 8);
    rl[rr] = 1.f / rs;
  }
  short* op = outb + ((size_t)(b * N_) + q0 + w * 16) * D_ + hh * DH_;
  #pragma unroll
  for (int rr = 0; rr < 4; rr++)
    #pragma unroll
    for (int dc = 0; dc < 4; dc++)
      op[(size_t)(quad * 4 + rr) * D_ + dc * 16 + l16] = f2bf(O[dc][rr] * rl[rr]);
}

extern "C" void kernel_launch(void* const* d_in, const int* in_sizes, int n_in,
                              void* d_out, int out_size, void* d_ws, size_t ws_size,
                              hipStream_t stream)
{
  const float* nf   = (const float*)d_in[0];
  const float* adj  = (const float*)d_in[1];
  const float* wdir = (const float*)d_in[2];
  const float* brg  = (const float*)d_in[3];
  const float* Wq   = (const float*)d_in[4];
  const float* Wk   = (const float*)d_in[5];
  const float* Wv   = (const float*)d_in[6];
  const float* Wo   = (const float*)d_in[7];
  const float* lng  = (const float*)d_in[8];
  const float* lnb  = (const float*)d_in[9];
  const float* ww   = (const float*)d_in[10];
  const float* wbb  = (const float*)d_in[11];
  float* out = (float*)d_out;

  short* xln   = (short*)d_ws;                        // M_*D_ (reused as attn out)
  short* WqkvT = xln   + (size_t)M_ * D_;             // 2688*896
  short* WoT   = WqkvT + (size_t)DQKV_ * D_;          // 896*896
  short* QKV   = WoT   + (size_t)D_ * D_;             // M_*2688
  unsigned* csb = (unsigned*)(QKV + (size_t)M_ * DQKV_); // 1024*1024 u32
  short* adjT  = (short*)(csb + (size_t)N_ * N_);     // 1024*1024 bf16

  ln_kernel<<<M_, 256, 0, stream>>>(nf, lng, lnb, xln);
  transpose_kernel<<<dim3(14, 14, 4), 256, 0, stream>>>(Wq, Wk, Wv, Wo, WqkvT, WoT);
  prep_kernel<<<dim3(16, 16), 256, 0, stream>>>(adj, brg, csb, adjT);
  gemm_bt<<<dim3(M_ / 128, DQKV_ / 128), 256, 0, stream>>>(xln, WqkvT, QKV, nullptr, nullptr, DQKV_);
  rope_kernel<<<(M_ * D_) / 256, 256, 0, stream>>>(QKV);
  attn_kernel<<<B_ * H_ * 8, 512, 0, stream>>>(QKV, csb, adjT, wdir, ww, wbb, xln);
  gemm_bt<<<dim3(M_ / 128, D_ / 128), 256, 0, stream>>>(xln, WoT, nullptr, out, nf, D_);
}